// Round 5
// baseline (68.574 us; speedup 1.0000x reference)
//
#include <hip/hip_runtime.h>
#include <hip/hip_bf16.h>

#define T_LEN 2400
#define LPC_N 16
#define FRAME 160
#define OPT   16                    // outputs per thread (160 % 16 == 0 -> one frame/thread)
#define GPR   (T_LEN / OPT)         // 150 groups per batch row
#define BLOCK 256

// sig: (B, 2400, 1) f32 in [0,255); lpc: (B, 15, 16) f32; out: (B, 2400, 1) f32
// One thread = 16 consecutive outputs. No LDS, no barrier. Needs samples
// [t-16, t+16): 8 aligned float4 loads (2x total redundancy, L1/L2-served),
// decode 32 samples in registers, 256 FMAs, 4 float4 stores.
__global__ __launch_bounds__(BLOCK)
void diff_pred_26319559589961_kernel(const float* __restrict__ sig,
                                     const float* __restrict__ lpc,
                                     float* __restrict__ out)
{
    const int g = blockIdx.x * BLOCK + threadIdx.x;   // global group id
    const int b = g / GPR;
    const int t = (g - b * GPR) * OPT;                // group start sample

    // ---- load 32 samples [t-16, t+16) : 8 independent dwordx4 ----
    float4 v[8];
    const float* sp = sig + (size_t)b * T_LEN + (t - LPC_N);
    #pragma unroll
    for (int j = 0; j < 8; ++j) {
        if (t - LPC_N + 4 * j >= 0)                   // only t==0 threads pad (j<4)
            v[j] = *(const float4*)(sp + 4 * j);
        else
            v[j] = make_float4(128.0f, 128.0f, 128.0f, 128.0f);  // decodes to 0
    }

    // ---- coeffs: one frame per thread ----
    const int frame = t / FRAME;
    const float4* c = (const float4*)(lpc + ((size_t)b * 15 + frame) * LPC_N);
    const float4 c0 = c[0], c1 = c[1], c2 = c[2], c3 = c[3];
    const float cf[16] = { c0.x, c0.y, c0.z, c0.w,
                           c1.x, c1.y, c1.z, c1.w,
                           c2.x, c2.y, c2.z, c2.w,
                           c3.x, c3.y, c3.z, c3.w };

    // ---- mu-law decode in registers ----
    // u2l(w) = copysign((32768/255) * (2^(|w-128|/16) - 1), w-128)
    float x[32];
    #pragma unroll
    for (int j = 0; j < 8; ++j) {
        const float* vp = &v[j].x;
        #pragma unroll
        for (int m = 0; m < 4; ++m) {
            const float u = vp[m] - 128.0f;
            x[4*j + m] = copysignf(
                (32768.0f/255.0f) * (exp2f(fabsf(u) * 0.0625f) - 1.0f), u);
        }
    }

    // ---- 16-tap prediction + l2u, 16 outputs, store as 4 float4 ----
    float* ob = out + (size_t)b * T_LEN + t;
    #pragma unroll
    for (int q = 0; q < 4; ++q) {
        float4 o;
        float* op = &o.x;
        #pragma unroll
        for (int kk = 0; kk < 4; ++kk) {
            const int k = 4 * q + kk;
            float acc = 0.0f;
            #pragma unroll
            for (int i = 0; i < LPC_N; ++i)
                acc += cf[i] * x[16 + k - i];
            const float pred = -acc;
            // l2u(p) = clip(128 + copysign(16*log2(1 + (255/32768)|p|), p), 0, 255)
            const float u = copysignf(
                16.0f * __log2f(1.0f + (255.0f/32768.0f) * fabsf(pred)), pred);
            op[kk] = fminf(fmaxf(128.0f + u, 0.0f), 255.0f);
        }
        *(float4*)(ob + 4 * q) = o;                   // global_store_dwordx4
    }
}

extern "C" void kernel_launch(void* const* d_in, const int* in_sizes, int n_in,
                              void* d_out, int out_size, void* d_ws, size_t ws_size,
                              hipStream_t stream) {
    const float* sig = (const float*)d_in[0];   // (B, 2400, 1)
    const float* lpc = (const float*)d_in[1];   // (B, 15, 16)
    float* out = (float*)d_out;                 // (B, 2400, 1)

    const int B = in_sizes[0] / T_LEN;          // 1024
    const int total = B * GPR;                  // 153600 threads
    diff_pred_26319559589961_kernel<<<total / BLOCK, BLOCK, 0, stream>>>(sig, lpc, out);
}